// Round 3
// baseline (43.168 us; speedup 1.0000x reference)
//
#include <hip/hip_runtime.h>
#include <math.h>

#define NB 4096
#define ND 128
#define NCS 8         // column splits
#define BI 32         // rows per block
#define BJ 512        // cols per block (4 waves x 128)

typedef __bf16 bf16x8 __attribute__((ext_vector_type(8)));
typedef __bf16 bf16x4 __attribute__((ext_vector_type(4)));
typedef float  f32x4  __attribute__((ext_vector_type(4)));

// ---- pass 1: L2-normalize rows, emit bf16 ----------------------------------
// 512 blocks x 256 thr; 32 lanes per row, float4 per lane
__global__ __launch_bounds__(256) void rownorm_kernel(
    const float* __restrict__ f, __bf16* __restrict__ fnb)
{
    const int t   = blockIdx.x * 256 + threadIdx.x;
    const int row = t >> 5;
    const int c   = (t & 31) << 2;
    float4 v = *reinterpret_cast<const float4*>(f + (size_t)row * ND + c);
    float ss = v.x * v.x + v.y * v.y + v.z * v.z + v.w * v.w;
#pragma unroll
    for (int off = 1; off < 32; off <<= 1) ss += __shfl_xor(ss, off, 64);
    const float inv = 1.0f / fmaxf(sqrtf(ss), 1e-12f);
    bf16x4 o;
    o[0] = (__bf16)(v.x * inv); o[1] = (__bf16)(v.y * inv);
    o[2] = (__bf16)(v.z * inv); o[3] = (__bf16)(v.w * inv);
    *reinterpret_cast<bf16x4*>(fnb + (size_t)row * ND + c) = o;
}

// ---- pass 2: sim-GEMM via MFMA + fused online stats -------------------------
// grid: blockIdx.x = bi*NCS + cs ; 256 thr = 4 waves, wave wc covers 128 cols
// block tile 32 x 512; wave tile 32 x 128
__global__ __launch_bounds__(256) void supcon_mfma(
    const __bf16* __restrict__ fn, const int* __restrict__ labels,
    float* __restrict__ partials)
{
    __shared__ float redL[4][BI][3];
    const int t    = threadIdx.x;
    const int wc   = t >> 6, lane = t & 63;
    const int bi   = blockIdx.x >> 3;          // 0..127
    const int cs   = blockIdx.x & (NCS - 1);   // 0..7
    const int ib   = bi * BI;
    const int jb   = cs * BJ + wc * 128;
    const int lr   = lane & 15;                // row/col residue in 16-tile
    const int lk   = lane >> 4;                // k-group 0..3

    // preload A fragments (16B contiguous per lane, row-major)
    bf16x8 a[2][4];
#pragma unroll
    for (int it = 0; it < 2; ++it)
#pragma unroll
        for (int ks = 0; ks < 4; ++ks)
            a[it][ks] = *reinterpret_cast<const bf16x8*>(
                fn + (size_t)(ib + it * 16 + lr) * ND + ks * 32 + lk * 8);

    int labi[2][4];
#pragma unroll
    for (int it = 0; it < 2; ++it)
#pragma unroll
        for (int r = 0; r < 4; ++r)
            labi[it][r] = labels[ib + it * 16 + lk * 4 + r];

    // hoist all j-tile labels out of the hot loop
    int labj8[8];
#pragma unroll
    for (int jt = 0; jt < 8; ++jt) labj8[jt] = labels[jb + jt * 16 + lr];

    float es[2][4] = {}, ps[2][4] = {}, np[2][4] = {};

#pragma unroll
    for (int jt = 0; jt < 8; ++jt) {
        bf16x8 b[4];
#pragma unroll
        for (int ks = 0; ks < 4; ++ks)
            b[ks] = *reinterpret_cast<const bf16x8*>(
                fn + (size_t)(jb + jt * 16 + lr) * ND + ks * 32 + lk * 8);
        f32x4 acc[2] = {};
#pragma unroll
        for (int ks = 0; ks < 4; ++ks) {
            acc[0] = __builtin_amdgcn_mfma_f32_16x16x32_bf16(a[0][ks], b[ks], acc[0], 0, 0, 0);
            acc[1] = __builtin_amdgcn_mfma_f32_16x16x32_bf16(a[1][ks], b[ks], acc[1], 0, 0, 0);
        }
        // fused epilogue: C/D layout col = lane&15, row = (lane>>4)*4 + r
        const int jg   = jb + jt * 16 + lr;
        const int labj = labj8[jt];
#pragma unroll
        for (int it = 0; it < 2; ++it)
#pragma unroll
            for (int r = 0; r < 4; ++r) {
                const int   ig   = ib + it * 16 + lk * 4 + r;
                const float s    = acc[it][r];
                const float e    = __expf(s);
                const bool  self = (jg == ig);
                const bool  pos  = (labj == labi[it][r]) && !self;
                es[it][r] += self ? 0.f : e;
                ps[it][r] += pos ? s : 0.f;
                np[it][r] += pos ? 1.f : 0.f;
            }
    }

    // reduce across the 16 col-lanes (offsets stay inside the 16-group)
#pragma unroll
    for (int off = 1; off < 16; off <<= 1)
#pragma unroll
        for (int it = 0; it < 2; ++it)
#pragma unroll
            for (int r = 0; r < 4; ++r) {
                es[it][r] += __shfl_xor(es[it][r], off, 64);
                ps[it][r] += __shfl_xor(ps[it][r], off, 64);
                np[it][r] += __shfl_xor(np[it][r], off, 64);
            }
    if (lr == 0) {
#pragma unroll
        for (int it = 0; it < 2; ++it)
#pragma unroll
            for (int r = 0; r < 4; ++r) {
                const int rl = it * 16 + lk * 4 + r;
                redL[wc][rl][0] = es[it][r];
                redL[wc][rl][1] = ps[it][r];
                redL[wc][rl][2] = np[it][r];
            }
    }
    __syncthreads();
    if (t < BI) {  // fold the 4 col-waves; one deterministic writer per (cs,row)
        float* p = partials + ((size_t)cs * NB + ib + t) * 3;
        p[0] = redL[0][t][0] + redL[1][t][0] + redL[2][t][0] + redL[3][t][0];
        p[1] = redL[0][t][1] + redL[1][t][1] + redL[2][t][1] + redL[3][t][1];
        p[2] = redL[0][t][2] + redL[1][t][2] + redL[2][t][2] + redL[3][t][2];
    }
}

// ---- pass 3: per-row loss + full reduce, single block, no atomics ----------
__global__ __launch_bounds__(1024) void final_kernel(
    const float* __restrict__ partials, float* __restrict__ out)
{
    const int t = threadIdx.x;
    float c = 0.f;
#pragma unroll
    for (int r = 0; r < 4; ++r) {
        const int row = t * 4 + r;
        float es = 0.f, ps = 0.f, np = 0.f;
#pragma unroll
        for (int cs = 0; cs < NCS; ++cs) {
            const float* p = partials + ((size_t)cs * NB + row) * 3;
            es += p[0]; ps += p[1]; np += p[2];
        }
        const float lse = logf(es);
        c += -(ps - np * lse) / ((np + 1e-5f) * (float)NB);
    }
#pragma unroll
    for (int off = 1; off < 64; off <<= 1) c += __shfl_xor(c, off, 64);
    __shared__ float sred[16];
    if ((t & 63) == 0) sred[t >> 6] = c;
    __syncthreads();
    if (t == 0) {
        float s = 0.f;
#pragma unroll
        for (int w = 0; w < 16; ++w) s += sred[w];
        out[0] = s;
    }
}

extern "C" void kernel_launch(void* const* d_in, const int* in_sizes, int n_in,
                              void* d_out, int out_size, void* d_ws, size_t ws_size,
                              hipStream_t stream) {
    const float* features = (const float*)d_in[0];
    const int*   labels   = (const int*)d_in[1];
    float* out = (float*)d_out;

    __bf16* fnb      = (__bf16*)d_ws;                                // 1 MB
    float*  partials = (float*)((char*)d_ws + (size_t)NB * ND * 2);  // 8*4096*3*4 = 393 KB

    rownorm_kernel<<<NB * 32 / 256, 256, 0, stream>>>(features, fnb);
    supcon_mfma<<<(NB / BI) * NCS, 256, 0, stream>>>(fnb, labels, partials);
    final_kernel<<<1, 1024, 0, stream>>>(partials, out);
}